// Round 14
// baseline (184.543 us; speedup 1.0000x reference)
//
#include <hip/hip_runtime.h>

#define EPS 1e-5f
#define SLOPE 0.01f

typedef short bf16x8 __attribute__((ext_vector_type(8)));
typedef float f32x4 __attribute__((ext_vector_type(4)));

static __device__ __forceinline__ unsigned short f2bf(float f) {
  unsigned u = __float_as_uint(f);
  unsigned r = (u + 0x7FFFu + ((u >> 16) & 1u)) >> 16;
  return (unsigned short)r;
}
#define BFLO(u) __uint_as_float((u) << 16)
#define BFHI(u) __uint_as_float((u) & 0xFFFF0000u)

// ================= CSR build: two-level counting sort =================
// bucket = dst >> 8 (256 nodes/bucket). hist fused with f32->bf16 cvt.
// fine_kernel emits padded col (node segments 4-aligned, pads -> row N)
// plus a 64-bucket histogram of nit=ceil(deg/4) for degree-sorting agg.

__global__ __launch_bounds__(1024) void hist_cvt_kernel(
    const int* __restrict__ dst, int* __restrict__ hist, int E, int NB,
    int histBlocks, const float* __restrict__ x, unsigned short* __restrict__ xb,
    unsigned short* __restrict__ h1b, int* __restrict__ nitcnt, int total4) {
  extern __shared__ int lh[];
  if ((int)blockIdx.x < histBlocks) {
    for (int i = threadIdx.x; i < NB; i += blockDim.x) lh[i] = 0;
    __syncthreads();
    int E4 = E >> 2;
    int stride = histBlocks * blockDim.x;
    const int4* d4 = (const int4*)dst;
    for (int i = blockIdx.x * blockDim.x + threadIdx.x; i < E4; i += stride) {
      int4 d = d4[i];
      atomicAdd(&lh[((unsigned)d.x) >> 8], 1);
      atomicAdd(&lh[((unsigned)d.y) >> 8], 1);
      atomicAdd(&lh[((unsigned)d.z) >> 8], 1);
      atomicAdd(&lh[((unsigned)d.w) >> 8], 1);
    }
    if (blockIdx.x == 0) {
      for (int i = (E4 << 2) + threadIdx.x; i < E; i += blockDim.x)
        atomicAdd(&lh[((unsigned)dst[i]) >> 8], 1);
    }
    __syncthreads();
    for (int b = threadIdx.x; b < NB; b += blockDim.x)
      hist[(size_t)b * histBlocks + blockIdx.x] = lh[b];
  } else {
    int cb = blockIdx.x - histBlocks;
    int tid = threadIdx.x;
    if (cb == 0) {  // side duties: zero nit counters + dummy rows N of xb/h1b
      ushort4 z4 = make_ushort4(0, 0, 0, 0);
      if (tid < 64) nitcnt[tid] = 0;
      else if (tid < 80) reinterpret_cast<ushort4*>(xb)[total4 + tid - 64] = z4;
      else if (tid < 96) reinterpret_cast<ushort4*>(h1b)[total4 + tid - 80] = z4;
    }
    int stride = (gridDim.x - histBlocks) * blockDim.x;
    for (int i = cb * blockDim.x + tid; i < total4; i += stride) {
      float4 v = reinterpret_cast<const float4*>(x)[i];
      ushort4 o;
      o.x = f2bf(v.x); o.y = f2bf(v.y); o.z = f2bf(v.z); o.w = f2bf(v.w);
      reinterpret_cast<ushort4*>(xb)[i] = o;
    }
  }
}

__global__ void scan_blk(const int* in, int* out, int* bsum, int n) {
  __shared__ int s[256];
  int i = blockIdx.x * 256 + threadIdx.x;
  int v = (i < n) ? in[i] : 0;
  s[threadIdx.x] = v;
  __syncthreads();
  for (int off = 1; off < 256; off <<= 1) {
    int t = (threadIdx.x >= off) ? s[threadIdx.x - off] : 0;
    __syncthreads();
    s[threadIdx.x] += t;
    __syncthreads();
  }
  if (i < n) out[i] = s[threadIdx.x] - v;
  if (threadIdx.x == 255) bsum[blockIdx.x] = s[255];
}

__global__ void scan_top(int* bsum, int nb) {
  __shared__ int s[512];
  int tid = threadIdx.x;
  int v = (tid < nb) ? bsum[tid] : 0;
  s[tid] = v;
  __syncthreads();
  for (int off = 1; off < 512; off <<= 1) {
    int t = (tid >= off) ? s[tid - off] : 0;
    __syncthreads();
    s[tid] += t;
    __syncthreads();
  }
  if (tid < nb) bsum[tid] = s[tid] - v;
}

__global__ __launch_bounds__(1024) void scatter_kernel(
    const int* __restrict__ src, const int* __restrict__ dst,
    const int* __restrict__ histS, const int* __restrict__ bsum,
    unsigned* __restrict__ binned, int E, int NB) {
  extern __shared__ int cur[];
  for (int b = threadIdx.x; b < NB; b += blockDim.x)
    cur[b] = histS[(size_t)b * gridDim.x + blockIdx.x] + bsum[b];
  __syncthreads();
  int E4 = E >> 2;
  int stride = gridDim.x * blockDim.x;
  const int4* d4 = (const int4*)dst;
  const int4* s4 = (const int4*)src;
  for (int i = blockIdx.x * blockDim.x + threadIdx.x; i < E4; i += stride) {
    int4 d = d4[i];
    int4 s = s4[i];
    int b0 = ((unsigned)d.x) >> 8;
    binned[atomicAdd(&cur[b0], 1)] = (unsigned)s.x | (((unsigned)d.x & 255u) << 20);
    int b1 = ((unsigned)d.y) >> 8;
    binned[atomicAdd(&cur[b1], 1)] = (unsigned)s.y | (((unsigned)d.y & 255u) << 20);
    int b2 = ((unsigned)d.z) >> 8;
    binned[atomicAdd(&cur[b2], 1)] = (unsigned)s.z | (((unsigned)d.z & 255u) << 20);
    int b3 = ((unsigned)d.w) >> 8;
    binned[atomicAdd(&cur[b3], 1)] = (unsigned)s.w | (((unsigned)d.w & 255u) << 20);
  }
  if (blockIdx.x == 0) {
    for (int i = (E4 << 2) + threadIdx.x; i < E; i += blockDim.x) {
      int d = dst[i];
      int b = ((unsigned)d) >> 8;
      binned[atomicAdd(&cur[b], 1)] = (unsigned)src[i] | (((unsigned)d & 255u) << 20);
    }
  }
}

// fine: padded per-node segments + nit histogram (for degree sort).
__global__ __launch_bounds__(256) void fine_kernel(
    const unsigned* __restrict__ binned, const int* __restrict__ histS,
    const int* __restrict__ bsum,
    int* __restrict__ degarr, int* __restrict__ pptr, int* __restrict__ col,
    int* __restrict__ nitcnt, int E, int NB, int NBLKB, int N) {
  __shared__ int ldeg[256];
  __shared__ int lcur[256];
  __shared__ int ss[256];
  __shared__ int nh[64];
  int b = blockIdx.x;
  int tid = threadIdx.x;
  int seg_s = histS[(size_t)b * NBLKB] + bsum[b];
  int seg_e = (b + 1 < NB) ? (histS[(size_t)(b + 1) * NBLKB] + bsum[b + 1]) : E;
  int pbase = (seg_s + b * 1024 + 3) & ~3;
  ldeg[tid] = 0;
  if (tid < 64) nh[tid] = 0;
  __syncthreads();
  for (int i = seg_s + tid; i < seg_e; i += 256)
    atomicAdd(&ldeg[(binned[i] >> 20) & 255u], 1);
  __syncthreads();
  int d = ldeg[tid];
  int pd = (d + 3) & ~3;
  ss[tid] = pd;
  __syncthreads();
  for (int off = 1; off < 256; off <<= 1) {
    int t = (tid >= off) ? ss[tid - off] : 0;
    __syncthreads();
    ss[tid] += t;
    __syncthreads();
  }
  int pstart = pbase + ss[tid] - pd;
  lcur[tid] = pstart;
  int node = (b << 8) + tid;
  if (node < N) {
    degarr[node] = d;
    pptr[node] = pstart;
    atomicAdd(&nh[min(pd >> 2, 63)], 1);
  }
  __syncthreads();
  if (tid < 64 && nh[tid]) atomicAdd(&nitcnt[tid], nh[tid]);
  for (int i = seg_s + tid; i < seg_e; i += 256) {
    unsigned v = binned[i];
    int pos = atomicAdd(&lcur[(v >> 20) & 255u], 1);
    col[pos] = (int)(v & 0xFFFFFu);
  }
  for (int k = d; k < pd; ++k) col[pstart + k] = N;  // pads -> zero row
}

// exclusive scan of the 64 nit buckets -> cursor bases
__global__ void nit_scan(const int* __restrict__ nitcnt, int* __restrict__ nitcur) {
  int tid = threadIdx.x;  // 64
  int v = nitcnt[tid];
  int x = v;
  #pragma unroll
  for (int o = 1; o < 64; o <<= 1) {
    int y = __shfl_up(x, o);
    if (tid >= o) x += y;
  }
  nitcur[tid] = x - v;
}

// build perm: nodes grouped by nit (block-local counting scatter)
__global__ __launch_bounds__(1024) void perm_kernel(
    const int* __restrict__ degarr, int* __restrict__ nitcur,
    int* __restrict__ perm, int N) {
  __shared__ int lh[64];
  __shared__ int lc[64];
  int tid = threadIdx.x;
  if (tid < 64) lh[tid] = 0;
  __syncthreads();
  int node = blockIdx.x * 1024 + tid;
  int bkt = 0;
  if (node < N) {
    bkt = min((degarr[node] + 3) >> 2, 63);
    atomicAdd(&lh[bkt], 1);
  }
  __syncthreads();
  if (tid < 64) lc[tid] = lh[tid] ? atomicAdd(&nitcur[tid], lh[tid]) : 0;
  __syncthreads();
  if (node < N) {
    int pos = atomicAdd(&lc[bkt], 1);
    perm[pos] = node;
  }
}

// ------- neighbor mean: 8 threads/node, degree-sorted order -------
// perm groups nodes of equal nit into the same wave -> no loop imbalance.

__global__ __launch_bounds__(256) void agg_kernel(
    const unsigned short* __restrict__ hb, const int* __restrict__ degarr,
    const int* __restrict__ pptr, const int* __restrict__ col,
    const int* __restrict__ perm, unsigned short* __restrict__ hm, int n) {
  int t = blockIdx.x * 256 + threadIdx.x;
  int idx = t >> 3;
  int fo = (t & 7) * 8;  // 8 features per lane
  if (idx >= n) return;
  int node = perm[idx];
  int deg = degarr[node];
  const int4* cp = reinterpret_cast<const int4*>(col + pptr[node]);
  int nit = (deg + 3) >> 2;
  float s0 = 0.f, s1 = 0.f, s2 = 0.f, s3 = 0.f;
  float s4 = 0.f, s5 = 0.f, s6 = 0.f, s7 = 0.f;
  for (int it = 0; it < nit; ++it) {
    int4 c = cp[it];
    uint4 u0 = *reinterpret_cast<const uint4*>(&hb[(size_t)c.x * 64 + fo]);
    uint4 u1 = *reinterpret_cast<const uint4*>(&hb[(size_t)c.y * 64 + fo]);
    uint4 u2 = *reinterpret_cast<const uint4*>(&hb[(size_t)c.z * 64 + fo]);
    uint4 u3 = *reinterpret_cast<const uint4*>(&hb[(size_t)c.w * 64 + fo]);
    s0 += BFLO(u0.x) + BFLO(u1.x) + BFLO(u2.x) + BFLO(u3.x);
    s1 += BFHI(u0.x) + BFHI(u1.x) + BFHI(u2.x) + BFHI(u3.x);
    s2 += BFLO(u0.y) + BFLO(u1.y) + BFLO(u2.y) + BFLO(u3.y);
    s3 += BFHI(u0.y) + BFHI(u1.y) + BFHI(u2.y) + BFHI(u3.y);
    s4 += BFLO(u0.z) + BFLO(u1.z) + BFLO(u2.z) + BFLO(u3.z);
    s5 += BFHI(u0.z) + BFHI(u1.z) + BFHI(u2.z) + BFHI(u3.z);
    s6 += BFLO(u0.w) + BFLO(u1.w) + BFLO(u2.w) + BFLO(u3.w);
    s7 += BFHI(u0.w) + BFHI(u1.w) + BFHI(u2.w) + BFHI(u3.w);
  }
  float inv = 1.0f / (float)(deg > 0 ? deg : 1);
  uint4 o;
  o.x = (unsigned)f2bf(s0 * inv) | ((unsigned)f2bf(s1 * inv) << 16);
  o.y = (unsigned)f2bf(s2 * inv) | ((unsigned)f2bf(s3 * inv) << 16);
  o.z = (unsigned)f2bf(s4 * inv) | ((unsigned)f2bf(s5 * inv) << 16);
  o.w = (unsigned)f2bf(s6 * inv) | ((unsigned)f2bf(s7 * inv) << 16);
  *reinterpret_cast<uint4*>(&hm[(size_t)node * 64 + fo]) = o;
}

// ========== streaming MFMA GEMM, bf16 z output ==========

__global__ __launch_bounds__(256) void gemm_stream(
    const unsigned short* __restrict__ A0,
    const unsigned short* __restrict__ A1,
    const float* __restrict__ Wself, const float* __restrict__ Wneigh,
    const float* __restrict__ bias,
    unsigned short* __restrict__ zb, float* __restrict__ partial, int n, int ntiles) {
  int tid = threadIdx.x;
  int lane = tid & 63;
  int w = tid >> 6;
  int l15 = lane & 15;
  int g = lane >> 4;

  bf16x8 B[4][4];
  #pragma unroll
  for (int t = 0; t < 4; ++t) {
    #pragma unroll
    for (int s = 0; s < 4; ++s) {
      const float* base = (s < 2 ? Wself : Wneigh) + (t * 16 + l15) * 64 + (s & 1) * 32 + g * 8;
      float4 w0 = *reinterpret_cast<const float4*>(base);
      float4 w1 = *reinterpret_cast<const float4*>(base + 4);
      bf16x8 b;
      b[0] = (short)f2bf(w0.x); b[1] = (short)f2bf(w0.y);
      b[2] = (short)f2bf(w0.z); b[3] = (short)f2bf(w0.w);
      b[4] = (short)f2bf(w1.x); b[5] = (short)f2bf(w1.y);
      b[6] = (short)f2bf(w1.z); b[7] = (short)f2bf(w1.w);
      B[t][s] = b;
    }
  }
  float bv[4];
  #pragma unroll
  for (int t = 0; t < 4; ++t) bv[t] = bias[t * 16 + l15];

  float ps[4] = {0.f, 0.f, 0.f, 0.f};
  float pq[4] = {0.f, 0.f, 0.f, 0.f};

  int nw = gridDim.x * 4;
  for (int tile = blockIdx.x * 4 + w; tile < ntiles; tile += nw) {
    int r0 = tile * 16 + l15;
    uint4 a[4];
    if (r0 < n) {
      const uint4* pa0 = reinterpret_cast<const uint4*>(A0 + (size_t)r0 * 64);
      const uint4* pa1 = reinterpret_cast<const uint4*>(A1 + (size_t)r0 * 64);
      a[0] = pa0[g]; a[1] = pa0[4 + g]; a[2] = pa1[g]; a[3] = pa1[4 + g];
    } else {
      a[0] = a[1] = a[2] = a[3] = make_uint4(0u, 0u, 0u, 0u);
    }
    f32x4 acc[4] = {};
    #pragma unroll
    for (int s = 0; s < 4; ++s) {
      bf16x8 af = *reinterpret_cast<bf16x8*>(&a[s]);
      #pragma unroll
      for (int t = 0; t < 4; ++t)
        acc[t] = __builtin_amdgcn_mfma_f32_16x16x32_bf16(af, B[t][s], acc[t], 0, 0, 0);
    }
    #pragma unroll
    for (int t = 0; t < 4; ++t) {
      #pragma unroll
      for (int i = 0; i < 4; ++i) {
        int gr = tile * 16 + g * 4 + i;
        if (gr < n) {
          float v = acc[t][i] + bv[t];
          zb[(size_t)gr * 64 + t * 16 + l15] = f2bf(v);
          ps[t] += v;
          pq[t] += v * v;
        }
      }
    }
  }

  #pragma unroll
  for (int t = 0; t < 4; ++t) {
    ps[t] += __shfl_xor(ps[t], 16); ps[t] += __shfl_xor(ps[t], 32);
    pq[t] += __shfl_xor(pq[t], 16); pq[t] += __shfl_xor(pq[t], 32);
  }
  __shared__ float sred[128];
  if (tid < 128) sred[tid] = 0.f;
  __syncthreads();
  if (lane < 16) {
    #pragma unroll
    for (int t = 0; t < 4; ++t) {
      atomicAdd(&sred[t * 16 + l15], ps[t]);
      atomicAdd(&sred[64 + t * 16 + l15], pq[t]);
    }
  }
  __syncthreads();
  if (tid < 128) partial[(size_t)blockIdx.x * 128 + tid] = sred[tid];
}

// reduce partials -> BN coefficients sc/sh directly.  grid = 64
__global__ __launch_bounds__(256) void reduce_coef(
    const float* __restrict__ partial, const float* __restrict__ gamma,
    const float* __restrict__ beta, float* __restrict__ coef, int nblk, float invN) {
  int f = blockIdx.x;
  float s = 0.f, q = 0.f;
  for (int j = threadIdx.x; j < nblk; j += 256) {
    s += partial[(size_t)j * 128 + f];
    q += partial[(size_t)j * 128 + 64 + f];
  }
  #pragma unroll
  for (int o = 1; o < 64; o <<= 1) {
    s += __shfl_xor(s, o);
    q += __shfl_xor(q, o);
  }
  __shared__ float rs[4], rq[4];
  if ((threadIdx.x & 63) == 0) {
    rs[threadIdx.x >> 6] = s;
    rq[threadIdx.x >> 6] = q;
  }
  __syncthreads();
  if (threadIdx.x == 0) {
    float S = rs[0] + rs[1] + rs[2] + rs[3];
    float Q = rq[0] + rq[1] + rq[2] + rq[3];
    float mu = S * invN;
    float var = Q * invN - mu * mu;
    float sc = rsqrtf(var + EPS) * gamma[f];
    coef[f] = sc;
    coef[64 + f] = beta[f] - mu * sc;
  }
}

// ---------------- BN (apply) + leaky relu ----------------

__global__ void bn_bf16_kernel(const unsigned short* __restrict__ zb,
                               const float* __restrict__ coef,
                               unsigned short* __restrict__ out, int n) {
  __shared__ float sc[64];
  __shared__ float sh[64];
  if (threadIdx.x < 64) {
    sc[threadIdx.x] = coef[threadIdx.x];
    sh[threadIdx.x] = coef[64 + threadIdx.x];
  }
  __syncthreads();
  int total = n * 16;
  int stride = gridDim.x * blockDim.x;
  for (int idx = blockIdx.x * blockDim.x + threadIdx.x; idx < total; idx += stride) {
    int f0 = (idx & 15) * 4;
    uint2 u = reinterpret_cast<const uint2*>(zb)[idx];
    float t;
    ushort4 o;
    t = BFLO(u.x) * sc[f0 + 0] + sh[f0 + 0]; o.x = f2bf(t > 0.f ? t : SLOPE * t);
    t = BFHI(u.x) * sc[f0 + 1] + sh[f0 + 1]; o.y = f2bf(t > 0.f ? t : SLOPE * t);
    t = BFLO(u.y) * sc[f0 + 2] + sh[f0 + 2]; o.z = f2bf(t > 0.f ? t : SLOPE * t);
    t = BFHI(u.y) * sc[f0 + 3] + sh[f0 + 3]; o.w = f2bf(t > 0.f ? t : SLOPE * t);
    reinterpret_cast<ushort4*>(out)[idx] = o;
  }
}

__global__ void bn_f32_kernel(const unsigned short* __restrict__ zb,
                              const float* __restrict__ coef,
                              float* __restrict__ out, int n) {
  __shared__ float sc[64];
  __shared__ float sh[64];
  if (threadIdx.x < 64) {
    sc[threadIdx.x] = coef[threadIdx.x];
    sh[threadIdx.x] = coef[64 + threadIdx.x];
  }
  __syncthreads();
  int total = n * 16;
  int stride = gridDim.x * blockDim.x;
  for (int idx = blockIdx.x * blockDim.x + threadIdx.x; idx < total; idx += stride) {
    int f0 = (idx & 15) * 4;
    uint2 u = reinterpret_cast<const uint2*>(zb)[idx];
    float4 o;
    float t;
    t = BFLO(u.x) * sc[f0 + 0] + sh[f0 + 0]; o.x = t > 0.f ? t : SLOPE * t;
    t = BFHI(u.x) * sc[f0 + 1] + sh[f0 + 1]; o.y = t > 0.f ? t : SLOPE * t;
    t = BFLO(u.y) * sc[f0 + 2] + sh[f0 + 2]; o.z = t > 0.f ? t : SLOPE * t;
    t = BFHI(u.y) * sc[f0 + 3] + sh[f0 + 3]; o.w = t > 0.f ? t : SLOPE * t;
    reinterpret_cast<float4*>(out)[idx] = o;
  }
}

// ---------------- launch ----------------

extern "C" void kernel_launch(void* const* d_in, const int* in_sizes, int n_in,
                              void* d_out, int out_size, void* d_ws, size_t ws_size,
                              hipStream_t stream) {
  const float* x  = (const float*)d_in[0];
  const int* ei   = (const int*)d_in[1];
  const float* Ws1 = (const float*)d_in[2];
  const float* Wn1 = (const float*)d_in[3];
  const float* b1  = (const float*)d_in[4];
  const float* g1  = (const float*)d_in[5];
  const float* be1 = (const float*)d_in[6];
  const float* Ws2 = (const float*)d_in[7];
  const float* Wn2 = (const float*)d_in[8];
  const float* b2  = (const float*)d_in[9];
  const float* g2  = (const float*)d_in[10];
  const float* be2 = (const float*)d_in[11];
  float* out = (float*)d_out;

  int N = in_sizes[0] / 64;
  int E = in_sizes[1] / 2;
  const int* src = ei;
  const int* dst = ei + E;

  int NB = (N + 255) >> 8;      // buckets of 256 nodes
  const int NBLKB = 256;        // hist/scatter parallel blocks (MUST stay 256)
  int M = NB * NBLKB;

  int ntiles = (N + 15) / 16;
  int gblk = (ntiles + 7) / 8;

  char* ws = (char*)d_ws;
  float* coef1 = (float*)ws;             // 128 (sc|sh, overwritten each call)
  float* coef2 = coef1 + 128;            // 128
  size_t off = 1024;
  auto take = [&](size_t bytes) {
    void* p = ws + off;
    off = (off + bytes + 255) & ~(size_t)255;
    return p;
  };
  int* hist   = (int*)take((size_t)M * 4);
  int* bsum   = (int*)take(512 * 4);
  int* degarr = (int*)take((size_t)N * 4);
  int* pptr   = (int*)take((size_t)N * 4);
  int* nitcnt = (int*)take(64 * 4);
  int* nitcur = (int*)take(64 * 4);
  int* perm   = (int*)take((size_t)N * 4);
  unsigned* binned = (unsigned*)take((size_t)E * 4);
  int* col    = (int*)take(((size_t)E + (size_t)NB * 1024 + 1024) * 4);
  unsigned short* xb  = (unsigned short*)take((size_t)(N + 1) * 64 * 2);
  unsigned short* hmb = (unsigned short*)take((size_t)N * 64 * 2);
  unsigned short* h1b = (unsigned short*)take((size_t)(N + 1) * 64 * 2);
  unsigned short* zb  = (unsigned short*)take((size_t)N * 64 * 2);
  float* partial = (float*)take((size_t)gblk * 128 * 4);

  // CSR build + cvt (fused; also zeroes nitcnt + dummy rows)
  hist_cvt_kernel<<<NBLKB + 128, 1024, NB * 4, stream>>>(dst, hist, E, NB, NBLKB,
                                                         x, xb, h1b, nitcnt, N * 16);
  int nb1 = (M + 255) / 256;  // == NB, one scan chunk per bucket
  scan_blk<<<nb1, 256, 0, stream>>>(hist, hist, bsum, M);
  scan_top<<<1, 512, 0, stream>>>(bsum, nb1);
  scatter_kernel<<<NBLKB, 1024, NB * 4, stream>>>(src, dst, hist, bsum, binned, E, NB);
  fine_kernel<<<NB, 256, 0, stream>>>(binned, hist, bsum, degarr, pptr, col,
                                      nitcnt, E, NB, NBLKB, N);
  nit_scan<<<1, 64, 0, stream>>>(nitcnt, nitcur);
  perm_kernel<<<(N + 1023) / 1024, 1024, 0, stream>>>(degarr, nitcur, perm, N);

  int ab = (N * 8 + 255) / 256;  // 32 nodes per 256-thread block
  float invN = 1.0f / (float)N;

  // layer 1
  agg_kernel<<<ab, 256, 0, stream>>>(xb, degarr, pptr, col, perm, hmb, N);
  gemm_stream<<<gblk, 256, 0, stream>>>(xb, hmb, Ws1, Wn1, b1, zb, partial, N, ntiles);
  reduce_coef<<<64, 256, 0, stream>>>(partial, g1, be1, coef1, gblk, invN);
  bn_bf16_kernel<<<2048, 256, 0, stream>>>(zb, coef1, h1b, N);

  // layer 2
  agg_kernel<<<ab, 256, 0, stream>>>(h1b, degarr, pptr, col, perm, hmb, N);
  gemm_stream<<<gblk, 256, 0, stream>>>(h1b, hmb, Ws2, Wn2, b2, zb, partial, N, ntiles);
  reduce_coef<<<64, 256, 0, stream>>>(partial, g2, be2, coef2, gblk, invN);
  bn_f32_kernel<<<2048, 256, 0, stream>>>(zb, coef2, out, N);
}

// Round 15
// 174.745 us; speedup vs baseline: 1.0561x; 1.0561x over previous
//
#include <hip/hip_runtime.h>

#define EPS 1e-5f
#define SLOPE 0.01f

typedef short bf16x8 __attribute__((ext_vector_type(8)));
typedef float f32x4 __attribute__((ext_vector_type(4)));

static __device__ __forceinline__ unsigned short f2bf(float f) {
  unsigned u = __float_as_uint(f);
  unsigned r = (u + 0x7FFFu + ((u >> 16) & 1u)) >> 16;
  return (unsigned short)r;
}
#define BFLO(u) __uint_as_float((u) << 16)
#define BFHI(u) __uint_as_float((u) & 0xFFFF0000u)

// ================= CSR build: two-level counting sort =================
// bucket = dst >> 8 (256 nodes/bucket). hist fused with f32->bf16 cvt.
// NBLKB == 256 so hist chunk index == bucket index (bsum[b] folding).

__global__ __launch_bounds__(1024) void hist_cvt_kernel(
    const int* __restrict__ dst, int* __restrict__ hist, int E, int NB,
    int histBlocks, const float* __restrict__ x, unsigned short* __restrict__ xb,
    int total4) {
  extern __shared__ int lh[];
  if ((int)blockIdx.x < histBlocks) {
    for (int i = threadIdx.x; i < NB; i += blockDim.x) lh[i] = 0;
    __syncthreads();
    int E4 = E >> 2;
    int stride = histBlocks * blockDim.x;
    const int4* d4 = (const int4*)dst;
    for (int i = blockIdx.x * blockDim.x + threadIdx.x; i < E4; i += stride) {
      int4 d = d4[i];
      atomicAdd(&lh[((unsigned)d.x) >> 8], 1);
      atomicAdd(&lh[((unsigned)d.y) >> 8], 1);
      atomicAdd(&lh[((unsigned)d.z) >> 8], 1);
      atomicAdd(&lh[((unsigned)d.w) >> 8], 1);
    }
    if (blockIdx.x == 0) {
      for (int i = (E4 << 2) + threadIdx.x; i < E; i += blockDim.x)
        atomicAdd(&lh[((unsigned)dst[i]) >> 8], 1);
    }
    __syncthreads();
    for (int b = threadIdx.x; b < NB; b += blockDim.x)
      hist[(size_t)b * histBlocks + blockIdx.x] = lh[b];
  } else {
    int cb = blockIdx.x - histBlocks;
    int stride = (gridDim.x - histBlocks) * blockDim.x;
    for (int i = cb * blockDim.x + threadIdx.x; i < total4; i += stride) {
      float4 v = reinterpret_cast<const float4*>(x)[i];
      ushort4 o;
      o.x = f2bf(v.x); o.y = f2bf(v.y); o.z = f2bf(v.z); o.w = f2bf(v.w);
      reinterpret_cast<ushort4*>(xb)[i] = o;
    }
  }
}

__global__ void scan_blk(const int* in, int* out, int* bsum, int n) {
  __shared__ int s[256];
  int i = blockIdx.x * 256 + threadIdx.x;
  int v = (i < n) ? in[i] : 0;
  s[threadIdx.x] = v;
  __syncthreads();
  for (int off = 1; off < 256; off <<= 1) {
    int t = (threadIdx.x >= off) ? s[threadIdx.x - off] : 0;
    __syncthreads();
    s[threadIdx.x] += t;
    __syncthreads();
  }
  if (i < n) out[i] = s[threadIdx.x] - v;
  if (threadIdx.x == 255) bsum[blockIdx.x] = s[255];
}

__global__ void scan_top(int* bsum, int nb) {
  __shared__ int s[512];
  int tid = threadIdx.x;
  int v = (tid < nb) ? bsum[tid] : 0;
  s[tid] = v;
  __syncthreads();
  for (int off = 1; off < 512; off <<= 1) {
    int t = (tid >= off) ? s[tid - off] : 0;
    __syncthreads();
    s[tid] += t;
    __syncthreads();
  }
  if (tid < nb) bsum[tid] = s[tid] - v;
}

// scatter: histS[b*256+blk] + bsum[b] = global base of this block's segment of bucket b
__global__ __launch_bounds__(1024) void scatter_kernel(
    const int* __restrict__ src, const int* __restrict__ dst,
    const int* __restrict__ histS, const int* __restrict__ bsum,
    unsigned* __restrict__ binned, int E, int NB) {
  extern __shared__ int cur[];
  for (int b = threadIdx.x; b < NB; b += blockDim.x)
    cur[b] = histS[(size_t)b * gridDim.x + blockIdx.x] + bsum[b];
  __syncthreads();
  int E4 = E >> 2;
  int stride = gridDim.x * blockDim.x;
  const int4* d4 = (const int4*)dst;
  const int4* s4 = (const int4*)src;
  for (int i = blockIdx.x * blockDim.x + threadIdx.x; i < E4; i += stride) {
    int4 d = d4[i];
    int4 s = s4[i];
    int b0 = ((unsigned)d.x) >> 8;
    binned[atomicAdd(&cur[b0], 1)] = (unsigned)s.x | (((unsigned)d.x & 255u) << 20);
    int b1 = ((unsigned)d.y) >> 8;
    binned[atomicAdd(&cur[b1], 1)] = (unsigned)s.y | (((unsigned)d.y & 255u) << 20);
    int b2 = ((unsigned)d.z) >> 8;
    binned[atomicAdd(&cur[b2], 1)] = (unsigned)s.z | (((unsigned)d.z & 255u) << 20);
    int b3 = ((unsigned)d.w) >> 8;
    binned[atomicAdd(&cur[b3], 1)] = (unsigned)s.w | (((unsigned)d.w & 255u) << 20);
  }
  if (blockIdx.x == 0) {
    for (int i = (E4 << 2) + threadIdx.x; i < E; i += blockDim.x) {
      int d = dst[i];
      int b = ((unsigned)d) >> 8;
      binned[atomicAdd(&cur[b], 1)] = (unsigned)src[i] | (((unsigned)d & 255u) << 20);
    }
  }
}

__global__ __launch_bounds__(256) void fine_kernel(
    const unsigned* __restrict__ binned, const int* __restrict__ histS,
    const int* __restrict__ bsum,
    int* __restrict__ rowptr, int* __restrict__ col, int E, int NB, int NBLKB, int N) {
  __shared__ int ldeg[256];
  __shared__ int lcur[256];
  __shared__ int ss[256];
  int b = blockIdx.x;
  int tid = threadIdx.x;
  int seg_s = histS[(size_t)b * NBLKB] + bsum[b];
  int seg_e = (b + 1 < NB) ? (histS[(size_t)(b + 1) * NBLKB] + bsum[b + 1]) : E;
  ldeg[tid] = 0;
  __syncthreads();
  for (int i = seg_s + tid; i < seg_e; i += 256)
    atomicAdd(&ldeg[(binned[i] >> 20) & 255u], 1);
  __syncthreads();
  int d = ldeg[tid];
  ss[tid] = d;
  __syncthreads();
  for (int off = 1; off < 256; off <<= 1) {
    int t = (tid >= off) ? ss[tid - off] : 0;
    __syncthreads();
    ss[tid] += t;
    __syncthreads();
  }
  int base = seg_s + ss[tid] - d;
  lcur[tid] = base;
  int node = (b << 8) + tid;
  if (node < N) rowptr[node] = base;
  if (b == NB - 1 && tid == 0) rowptr[N] = E;  // sentinel
  __syncthreads();
  for (int i = seg_s + tid; i < seg_e; i += 256) {
    unsigned v = binned[i];
    int pos = atomicAdd(&lcur[(v >> 20) & 255u], 1);
    col[pos] = (int)(v & 0xFFFFFu);
  }
}

// ------- neighbor mean: 8 threads/node, uint4 gathers, unroll-4 -------
// Round-9 exact form: plain launch_bounds(256), compiler picks ~56 VGPR
// (8 waves/SIMD). Gather-BW bound (~2 TB/s random 128B rows) — ILP-8,
// padding, degree-sort all measured neutral-to-worse (rounds 8,13,14).

__global__ __launch_bounds__(256) void agg_kernel(
    const unsigned short* __restrict__ hb, const int* __restrict__ rowptr,
    const int* __restrict__ col, unsigned short* __restrict__ hm, int n) {
  int t = blockIdx.x * 256 + threadIdx.x;
  int node = t >> 3;
  int fo = (t & 7) * 8;  // 8 features per lane
  if (node >= n) return;
  int beg = rowptr[node];
  int end = rowptr[node + 1];
  float s0 = 0.f, s1 = 0.f, s2 = 0.f, s3 = 0.f;
  float s4 = 0.f, s5 = 0.f, s6 = 0.f, s7 = 0.f;
  int e = beg;
  for (; e + 4 <= end; e += 4) {
    int i0 = col[e], i1 = col[e + 1], i2 = col[e + 2], i3 = col[e + 3];
    uint4 u0 = *reinterpret_cast<const uint4*>(&hb[(size_t)i0 * 64 + fo]);
    uint4 u1 = *reinterpret_cast<const uint4*>(&hb[(size_t)i1 * 64 + fo]);
    uint4 u2 = *reinterpret_cast<const uint4*>(&hb[(size_t)i2 * 64 + fo]);
    uint4 u3 = *reinterpret_cast<const uint4*>(&hb[(size_t)i3 * 64 + fo]);
    s0 += BFLO(u0.x) + BFLO(u1.x) + BFLO(u2.x) + BFLO(u3.x);
    s1 += BFHI(u0.x) + BFHI(u1.x) + BFHI(u2.x) + BFHI(u3.x);
    s2 += BFLO(u0.y) + BFLO(u1.y) + BFLO(u2.y) + BFLO(u3.y);
    s3 += BFHI(u0.y) + BFHI(u1.y) + BFHI(u2.y) + BFHI(u3.y);
    s4 += BFLO(u0.z) + BFLO(u1.z) + BFLO(u2.z) + BFLO(u3.z);
    s5 += BFHI(u0.z) + BFHI(u1.z) + BFHI(u2.z) + BFHI(u3.z);
    s6 += BFLO(u0.w) + BFLO(u1.w) + BFLO(u2.w) + BFLO(u3.w);
    s7 += BFHI(u0.w) + BFHI(u1.w) + BFHI(u2.w) + BFHI(u3.w);
  }
  for (; e < end; ++e) {
    uint4 u = *reinterpret_cast<const uint4*>(&hb[(size_t)col[e] * 64 + fo]);
    s0 += BFLO(u.x); s1 += BFHI(u.x);
    s2 += BFLO(u.y); s3 += BFHI(u.y);
    s4 += BFLO(u.z); s5 += BFHI(u.z);
    s6 += BFLO(u.w); s7 += BFHI(u.w);
  }
  int deg = end - beg;
  float inv = 1.0f / (float)(deg > 0 ? deg : 1);
  uint4 o;
  o.x = (unsigned)f2bf(s0 * inv) | ((unsigned)f2bf(s1 * inv) << 16);
  o.y = (unsigned)f2bf(s2 * inv) | ((unsigned)f2bf(s3 * inv) << 16);
  o.z = (unsigned)f2bf(s4 * inv) | ((unsigned)f2bf(s5 * inv) << 16);
  o.w = (unsigned)f2bf(s6 * inv) | ((unsigned)f2bf(s7 * inv) << 16);
  *reinterpret_cast<uint4*>(&hm[(size_t)node * 64 + fo]) = o;
}

// ========== streaming MFMA GEMM, bf16 z output ==========

__global__ __launch_bounds__(256) void gemm_stream(
    const unsigned short* __restrict__ A0,
    const unsigned short* __restrict__ A1,
    const float* __restrict__ Wself, const float* __restrict__ Wneigh,
    const float* __restrict__ bias,
    unsigned short* __restrict__ zb, float* __restrict__ partial, int n, int ntiles) {
  int tid = threadIdx.x;
  int lane = tid & 63;
  int w = tid >> 6;
  int l15 = lane & 15;
  int g = lane >> 4;

  bf16x8 B[4][4];
  #pragma unroll
  for (int t = 0; t < 4; ++t) {
    #pragma unroll
    for (int s = 0; s < 4; ++s) {
      const float* base = (s < 2 ? Wself : Wneigh) + (t * 16 + l15) * 64 + (s & 1) * 32 + g * 8;
      float4 w0 = *reinterpret_cast<const float4*>(base);
      float4 w1 = *reinterpret_cast<const float4*>(base + 4);
      bf16x8 b;
      b[0] = (short)f2bf(w0.x); b[1] = (short)f2bf(w0.y);
      b[2] = (short)f2bf(w0.z); b[3] = (short)f2bf(w0.w);
      b[4] = (short)f2bf(w1.x); b[5] = (short)f2bf(w1.y);
      b[6] = (short)f2bf(w1.z); b[7] = (short)f2bf(w1.w);
      B[t][s] = b;
    }
  }
  float bv[4];
  #pragma unroll
  for (int t = 0; t < 4; ++t) bv[t] = bias[t * 16 + l15];

  float ps[4] = {0.f, 0.f, 0.f, 0.f};
  float pq[4] = {0.f, 0.f, 0.f, 0.f};

  int nw = gridDim.x * 4;
  for (int tile = blockIdx.x * 4 + w; tile < ntiles; tile += nw) {
    int r0 = tile * 16 + l15;
    uint4 a[4];
    if (r0 < n) {
      const uint4* pa0 = reinterpret_cast<const uint4*>(A0 + (size_t)r0 * 64);
      const uint4* pa1 = reinterpret_cast<const uint4*>(A1 + (size_t)r0 * 64);
      a[0] = pa0[g]; a[1] = pa0[4 + g]; a[2] = pa1[g]; a[3] = pa1[4 + g];
    } else {
      a[0] = a[1] = a[2] = a[3] = make_uint4(0u, 0u, 0u, 0u);
    }
    f32x4 acc[4] = {};
    #pragma unroll
    for (int s = 0; s < 4; ++s) {
      bf16x8 af = *reinterpret_cast<bf16x8*>(&a[s]);
      #pragma unroll
      for (int t = 0; t < 4; ++t)
        acc[t] = __builtin_amdgcn_mfma_f32_16x16x32_bf16(af, B[t][s], acc[t], 0, 0, 0);
    }
    #pragma unroll
    for (int t = 0; t < 4; ++t) {
      #pragma unroll
      for (int i = 0; i < 4; ++i) {
        int gr = tile * 16 + g * 4 + i;
        if (gr < n) {
          float v = acc[t][i] + bv[t];
          zb[(size_t)gr * 64 + t * 16 + l15] = f2bf(v);
          ps[t] += v;
          pq[t] += v * v;
        }
      }
    }
  }

  #pragma unroll
  for (int t = 0; t < 4; ++t) {
    ps[t] += __shfl_xor(ps[t], 16); ps[t] += __shfl_xor(ps[t], 32);
    pq[t] += __shfl_xor(pq[t], 16); pq[t] += __shfl_xor(pq[t], 32);
  }
  __shared__ float sred[128];
  if (tid < 128) sred[tid] = 0.f;
  __syncthreads();
  if (lane < 16) {
    #pragma unroll
    for (int t = 0; t < 4; ++t) {
      atomicAdd(&sred[t * 16 + l15], ps[t]);
      atomicAdd(&sred[64 + t * 16 + l15], pq[t]);
    }
  }
  __syncthreads();
  if (tid < 128) partial[(size_t)blockIdx.x * 128 + tid] = sred[tid];
}

// reduce partials -> BN coefficients sc/sh directly.  grid = 64
__global__ __launch_bounds__(256) void reduce_coef(
    const float* __restrict__ partial, const float* __restrict__ gamma,
    const float* __restrict__ beta, float* __restrict__ coef, int nblk, float invN) {
  int f = blockIdx.x;
  float s = 0.f, q = 0.f;
  for (int j = threadIdx.x; j < nblk; j += 256) {
    s += partial[(size_t)j * 128 + f];
    q += partial[(size_t)j * 128 + 64 + f];
  }
  #pragma unroll
  for (int o = 1; o < 64; o <<= 1) {
    s += __shfl_xor(s, o);
    q += __shfl_xor(q, o);
  }
  __shared__ float rs[4], rq[4];
  if ((threadIdx.x & 63) == 0) {
    rs[threadIdx.x >> 6] = s;
    rq[threadIdx.x >> 6] = q;
  }
  __syncthreads();
  if (threadIdx.x == 0) {
    float S = rs[0] + rs[1] + rs[2] + rs[3];
    float Q = rq[0] + rq[1] + rq[2] + rq[3];
    float mu = S * invN;
    float var = Q * invN - mu * mu;
    float sc = rsqrtf(var + EPS) * gamma[f];
    coef[f] = sc;
    coef[64 + f] = beta[f] - mu * sc;
  }
}

// ---------------- BN (apply) + leaky relu ----------------

__global__ void bn_bf16_kernel(const unsigned short* __restrict__ zb,
                               const float* __restrict__ coef,
                               unsigned short* __restrict__ out, int n) {
  __shared__ float sc[64];
  __shared__ float sh[64];
  if (threadIdx.x < 64) {
    sc[threadIdx.x] = coef[threadIdx.x];
    sh[threadIdx.x] = coef[64 + threadIdx.x];
  }
  __syncthreads();
  int total = n * 16;
  int stride = gridDim.x * blockDim.x;
  for (int idx = blockIdx.x * blockDim.x + threadIdx.x; idx < total; idx += stride) {
    int f0 = (idx & 15) * 4;
    uint2 u = reinterpret_cast<const uint2*>(zb)[idx];
    float t;
    ushort4 o;
    t = BFLO(u.x) * sc[f0 + 0] + sh[f0 + 0]; o.x = f2bf(t > 0.f ? t : SLOPE * t);
    t = BFHI(u.x) * sc[f0 + 1] + sh[f0 + 1]; o.y = f2bf(t > 0.f ? t : SLOPE * t);
    t = BFLO(u.y) * sc[f0 + 2] + sh[f0 + 2]; o.z = f2bf(t > 0.f ? t : SLOPE * t);
    t = BFHI(u.y) * sc[f0 + 3] + sh[f0 + 3]; o.w = f2bf(t > 0.f ? t : SLOPE * t);
    reinterpret_cast<ushort4*>(out)[idx] = o;
  }
}

__global__ void bn_f32_kernel(const unsigned short* __restrict__ zb,
                              const float* __restrict__ coef,
                              float* __restrict__ out, int n) {
  __shared__ float sc[64];
  __shared__ float sh[64];
  if (threadIdx.x < 64) {
    sc[threadIdx.x] = coef[threadIdx.x];
    sh[threadIdx.x] = coef[64 + threadIdx.x];
  }
  __syncthreads();
  int total = n * 16;
  int stride = gridDim.x * blockDim.x;
  for (int idx = blockIdx.x * blockDim.x + threadIdx.x; idx < total; idx += stride) {
    int f0 = (idx & 15) * 4;
    uint2 u = reinterpret_cast<const uint2*>(zb)[idx];
    float4 o;
    float t;
    t = BFLO(u.x) * sc[f0 + 0] + sh[f0 + 0]; o.x = t > 0.f ? t : SLOPE * t;
    t = BFHI(u.x) * sc[f0 + 1] + sh[f0 + 1]; o.y = t > 0.f ? t : SLOPE * t;
    t = BFLO(u.y) * sc[f0 + 2] + sh[f0 + 2]; o.z = t > 0.f ? t : SLOPE * t;
    t = BFHI(u.y) * sc[f0 + 3] + sh[f0 + 3]; o.w = t > 0.f ? t : SLOPE * t;
    reinterpret_cast<float4*>(out)[idx] = o;
  }
}

// ---------------- launch ----------------

extern "C" void kernel_launch(void* const* d_in, const int* in_sizes, int n_in,
                              void* d_out, int out_size, void* d_ws, size_t ws_size,
                              hipStream_t stream) {
  const float* x  = (const float*)d_in[0];
  const int* ei   = (const int*)d_in[1];
  const float* Ws1 = (const float*)d_in[2];
  const float* Wn1 = (const float*)d_in[3];
  const float* b1  = (const float*)d_in[4];
  const float* g1  = (const float*)d_in[5];
  const float* be1 = (const float*)d_in[6];
  const float* Ws2 = (const float*)d_in[7];
  const float* Wn2 = (const float*)d_in[8];
  const float* b2  = (const float*)d_in[9];
  const float* g2  = (const float*)d_in[10];
  const float* be2 = (const float*)d_in[11];
  float* out = (float*)d_out;

  int N = in_sizes[0] / 64;
  int E = in_sizes[1] / 2;
  const int* src = ei;
  const int* dst = ei + E;

  int NB = (N + 255) >> 8;      // buckets of 256 nodes
  const int NBLKB = 256;        // hist/scatter parallel blocks (MUST stay 256)
  int M = NB * NBLKB;

  int ntiles = (N + 15) / 16;
  int gblk = (ntiles + 7) / 8;

  char* ws = (char*)d_ws;
  float* coef1 = (float*)ws;             // 128 (sc|sh, overwritten each call)
  float* coef2 = coef1 + 128;            // 128
  size_t off = 1024;
  auto take = [&](size_t bytes) {
    void* p = ws + off;
    off = (off + bytes + 255) & ~(size_t)255;
    return p;
  };
  int* hist   = (int*)take((size_t)M * 4);
  int* bsum   = (int*)take(512 * 4);
  int* rowptr = (int*)take((size_t)(N + 1) * 4);
  unsigned* binned = (unsigned*)take((size_t)E * 4);
  int* col    = (int*)take((size_t)E * 4);
  unsigned short* xb  = (unsigned short*)take((size_t)N * 64 * 2);
  unsigned short* hmb = (unsigned short*)take((size_t)N * 64 * 2);
  unsigned short* h1b = (unsigned short*)take((size_t)N * 64 * 2);
  unsigned short* zb  = (unsigned short*)take((size_t)N * 64 * 2);
  float* partial = (float*)take((size_t)gblk * 128 * 4);

  // CSR build + cvt (fused)
  hist_cvt_kernel<<<NBLKB + 128, 1024, NB * 4, stream>>>(dst, hist, E, NB, NBLKB,
                                                         x, xb, N * 16);
  int nb1 = (M + 255) / 256;  // == NB, one scan chunk per bucket
  scan_blk<<<nb1, 256, 0, stream>>>(hist, hist, bsum, M);
  scan_top<<<1, 512, 0, stream>>>(bsum, nb1);
  scatter_kernel<<<NBLKB, 1024, NB * 4, stream>>>(src, dst, hist, bsum, binned, E, NB);
  fine_kernel<<<NB, 256, 0, stream>>>(binned, hist, bsum, rowptr, col, E, NB, NBLKB, N);

  int ab = (N * 8 + 255) / 256;  // 32 nodes per 256-thread block
  float invN = 1.0f / (float)N;

  // layer 1
  agg_kernel<<<ab, 256, 0, stream>>>(xb, rowptr, col, hmb, N);
  gemm_stream<<<gblk, 256, 0, stream>>>(xb, hmb, Ws1, Wn1, b1, zb, partial, N, ntiles);
  reduce_coef<<<64, 256, 0, stream>>>(partial, g1, be1, coef1, gblk, invN);
  bn_bf16_kernel<<<2048, 256, 0, stream>>>(zb, coef1, h1b, N);

  // layer 2
  agg_kernel<<<ab, 256, 0, stream>>>(h1b, rowptr, col, hmb, N);
  gemm_stream<<<gblk, 256, 0, stream>>>(h1b, hmb, Ws2, Wn2, b2, zb, partial, N, ntiles);
  reduce_coef<<<64, 256, 0, stream>>>(partial, g2, be2, coef2, gblk, invN);
  bn_f32_kernel<<<2048, 256, 0, stream>>>(zb, coef2, out, N);
}